// Round 2
// baseline (202.809 us; speedup 1.0000x reference)
//
#include <hip/hip_runtime.h>

// uDTW forward DP, R10 (resubmit — round-1 failure was container infra, not
// the kernel): two-rows-per-lane restructure of R9.
// Lane t owns rows 2t (A, i=2t+1) and 2t+1 (B, i=2t+2):
//  - row B's deps are lane-local row-A state (current + 1-step-delayed copies
//    eA1/dA1) => no DPP for row B, two independent chains per step (ILP-2).
//  - 256 threads / 4 waves => 1 wave per SIMD (no intra-SIMD issue
//    contention), 4-stage pipeline, PHASES = 32+3 = 35 (was 39).
//  - funnel: row-A shift is always {0,2}, row-B always {1,3} => one cndmask
//    stage per row (32 selects/row/burst, was 65/row).
//  - publish: adjacent lanes' boundary cols differ by 2 => float2 publish
//    would be 16B-stride b64 (R8's 8-way conflict). Split edge into separate
//    E and D float planes: b32 stores at 8B stride = 2-way = free; consumer
//    float4 reads stay 16B-aligned (base = 128+32B-128w, mult of 4).
// Per-cell arithmetic order identical to R9 (same fma/add/EPS order).

constexpr int N = 512;
constexpr int M = 512;
constexpr int BATCH = 32;
constexpr int NM = N + M;                  // 1024; diags d = 2..NM
constexpr int K = 32;                      // diagonals per burst
constexpr int NB = 32;                     // bursts cover d = 2..1025
constexpr int PHASES = NB + 3;             // 35
constexpr float NL2E = -1.4426950408889634f;   // -log2(e)
constexpr float NLN2 = -0.6931471805599453f;   // -ln(2)
constexpr float EPS  = 1e-30f;

__device__ __forceinline__ float lane_shr1_or(float oldv, float x) {
  // lane n gets lane n-1's x; lane 0 keeps oldv (bound_ctrl=false).
  return __int_as_float(__builtin_amdgcn_update_dpp(
      __float_as_int(oldv), __float_as_int(x), 0x138, 0xf, 0xf, false));
}
__device__ __forceinline__ int qclamp(int q) {
  return q < 0 ? 0 : (q > 127 ? 127 : q);
}

__global__ __launch_bounds__(256, 1)
void softdtw_fwd(const float* __restrict__ D,
                 const float* __restrict__ Sig,
                 float* __restrict__ out) {
  const int b = blockIdx.x;
  const int t = threadIdx.x;           // owns rows 2t (A) and 2t+1 (B)
  const int w = t >> 6;                // wave 0..3
  const float4* DrowA4 = (const float4*)(D + ((size_t)b * N + 2 * t) * M);
  const float4* DrowB4 = (const float4*)(D + ((size_t)b * N + 2 * t + 1) * M);

  // edge*[w][128 + c] = E / scaled-D of row 128(w+1) at column c (c = j-1).
  // 128-halo absorbs invalid-step writes (E there is exp2(-1e30)=0).
  __shared__ float edgeE[4][768];
  __shared__ float edgeD[4][768];
  for (int idx = t; idx < 4 * 768; idx += 256) {
    (&edgeE[0][0])[idx] = 0.f;
    (&edgeD[0][0])[idx] = 0.f;
  }

  // carried state (D values pre-scaled by NL2E; carried/published raw,
  // consumers multiply by masked-zero E)
  float eSelfA = 0.f, dSelfA = 0.f;            // row A at prev diag
  float eA1 = 0.f, dA1 = 0.f;                  // row A, one step further back
  float eN2A = (t == 0) ? 1.f : 0.f;           // neighbor (i-1) at d-2; E(0,0)=1
  float dN2A = 0.f;
  float eSelfB = 0.f, dSelfB = 0.f;            // row B at prev diag

  // Sig contributes only via 4 elements at the final cell (row B of t=255)
  float sgA = 0.f, sg0 = 0.f, sg1 = 0.f, sg2 = 0.f;
  if (t == 255) {
    const float* Sb = Sig + (size_t)b * N * M;
    sgA = Sb[(size_t)(N - 1) * M + (M - 1)];
    sg0 = Sb[(size_t)(N - 2) * M + (M - 2)];
    sg1 = Sb[(size_t)(N - 2) * M + (M - 1)];
    sg2 = Sb[(size_t)(N - 1) * M + (M - 2)];
  }

  const int Bl = 4 * w, Bh = 4 * w + 19;   // active bursts for this wave
  const bool sA2 = (t & 1) != 0;           // row-A funnel: shift {0,2}
  const bool sB2 = (t & 1) == 0;           // row-B funnel: shift {1,3}

  // current-burst D windows: 9 quads per row
  float4 u0,u1,u2,u3,u4,u5,u6,u7,u8;       // row A
  float4 v0,v1,v2,v3,v4,v5,v6,v7,v8;       // row B
  {
    const int qa = (32 * Bl - 2 * t) >> 2;
    u0 = DrowA4[qclamp(qa + 0)]; u1 = DrowA4[qclamp(qa + 1)];
    u2 = DrowA4[qclamp(qa + 2)]; u3 = DrowA4[qclamp(qa + 3)];
    u4 = DrowA4[qclamp(qa + 4)]; u5 = DrowA4[qclamp(qa + 5)];
    u6 = DrowA4[qclamp(qa + 6)]; u7 = DrowA4[qclamp(qa + 7)];
    u8 = DrowA4[qclamp(qa + 8)];
    const int qb = (32 * Bl - 2 * t - 1) >> 2;
    v0 = DrowB4[qclamp(qb + 0)]; v1 = DrowB4[qclamp(qb + 1)];
    v2 = DrowB4[qclamp(qb + 2)]; v3 = DrowB4[qclamp(qb + 3)];
    v4 = DrowB4[qclamp(qb + 4)]; v5 = DrowB4[qclamp(qb + 5)];
    v6 = DrowB4[qclamp(qb + 6)]; v7 = DrowB4[qclamp(qb + 7)];
    v8 = DrowB4[qclamp(qb + 8)];
  }
  __syncthreads();

  for (int p = 0; p < PHASES; ++p) {
    const int B = p - w;
    const int nB = B + 1;
    const bool dopre = (nB >= Bl) && (nB <= Bh);   // wave-uniform

    // ---- prefetch next burst's D quads (consumed after the barrier)
    float4 pu0,pu1,pu2,pu3,pu4,pu5,pu6,pu7,pu8;
    float4 pv0,pv1,pv2,pv3,pv4,pv5,pv6,pv7,pv8;
    if (dopre) {
      const int qa = (32 * nB - 2 * t) >> 2;
      pu0 = DrowA4[qclamp(qa + 0)]; pu1 = DrowA4[qclamp(qa + 1)];
      pu2 = DrowA4[qclamp(qa + 2)]; pu3 = DrowA4[qclamp(qa + 3)];
      pu4 = DrowA4[qclamp(qa + 4)]; pu5 = DrowA4[qclamp(qa + 5)];
      pu6 = DrowA4[qclamp(qa + 6)]; pu7 = DrowA4[qclamp(qa + 7)];
      pu8 = DrowA4[qclamp(qa + 8)];
      const int qb = (32 * nB - 2 * t - 1) >> 2;
      pv0 = DrowB4[qclamp(qb + 0)]; pv1 = DrowB4[qclamp(qb + 1)];
      pv2 = DrowB4[qclamp(qb + 2)]; pv3 = DrowB4[qclamp(qb + 3)];
      pv4 = DrowB4[qclamp(qb + 4)]; pv5 = DrowB4[qclamp(qb + 5)];
      pv6 = DrowB4[qclamp(qb + 6)]; pv7 = DrowB4[qclamp(qb + 7)];
      pv8 = DrowB4[qclamp(qb + 8)];
    }

    if (B >= Bl && B <= Bh) {
      const int d0 = 2 + B * K;
      const int cA0 = 32 * B - 2 * t;    // row-A column index base (c = j-1)

      // ---- neighbor boundary preload: 8+8 float4 (32 E + 32 D), 16B-aligned
      float4 nE0,nE1,nE2,nE3,nE4,nE5,nE6,nE7;
      float4 nD0,nD1,nD2,nD3,nD4,nD5,nD6,nD7;
      if (w > 0) {
        const int ebase = 32 * B - 128 * w + 128;
        const float4* epE = (const float4*)&edgeE[w - 1][ebase];
        const float4* epD = (const float4*)&edgeD[w - 1][ebase];
        nE0 = epE[0]; nE1 = epE[1]; nE2 = epE[2]; nE3 = epE[3];
        nE4 = epE[4]; nE5 = epE[5]; nE6 = epE[6]; nE7 = epE[7];
        nD0 = epD[0]; nD1 = epD[1]; nD2 = epD[2]; nD3 = epD[3];
        nD4 = epD[4]; nD5 = epD[5]; nD6 = epD[6]; nD7 = epD[7];
      } else {
        const float4 z = make_float4(0.f, 0.f, 0.f, 0.f);
        nE0=z;nE1=z;nE2=z;nE3=z;nE4=z;nE5=z;nE6=z;nE7=z;
        nD0=z;nD1=z;nD2=z;nD3=z;nD4=z;nD5=z;nD6=z;nD7=z;
      }

      // ---- unpack windows
      const float
        A0=u0.x, A1=u0.y, A2=u0.z, A3=u0.w,  A4=u1.x, A5=u1.y, A6=u1.z, A7=u1.w,
        A8=u2.x, A9=u2.y, A10=u2.z, A11=u2.w, A12=u3.x, A13=u3.y, A14=u3.z, A15=u3.w,
        A16=u4.x, A17=u4.y, A18=u4.z, A19=u4.w, A20=u5.x, A21=u5.y, A22=u5.z, A23=u5.w,
        A24=u6.x, A25=u6.y, A26=u6.z, A27=u6.w, A28=u7.x, A29=u7.y, A30=u7.z, A31=u7.w,
        A32=u8.x, A33=u8.y;
      const float
        F1=v0.y, F2=v0.z, F3=v0.w,  F4=v1.x, F5=v1.y, F6=v1.z, F7=v1.w,
        F8=v2.x, F9=v2.y, F10=v2.z, F11=v2.w, F12=v3.x, F13=v3.y, F14=v3.z, F15=v3.w,
        F16=v4.x, F17=v4.y, F18=v4.z, F19=v4.w, F20=v5.x, F21=v5.y, F22=v5.z, F23=v5.w,
        F24=v6.x, F25=v6.y, F26=v6.z, F27=v6.w, F28=v7.x, F29=v7.y, F30=v7.z, F31=v7.w,
        F32=v8.x, F33=v8.y, F34=v8.z;

      // ---- funnel align: gA_k = D_A[cA0+k], gB_k = D_B[cA0-1+k]
      const float
        gA0 =sA2?A2 :A0,  gA1 =sA2?A3 :A1,  gA2 =sA2?A4 :A2,  gA3 =sA2?A5 :A3,
        gA4 =sA2?A6 :A4,  gA5 =sA2?A7 :A5,  gA6 =sA2?A8 :A6,  gA7 =sA2?A9 :A7,
        gA8 =sA2?A10:A8,  gA9 =sA2?A11:A9,  gA10=sA2?A12:A10, gA11=sA2?A13:A11,
        gA12=sA2?A14:A12, gA13=sA2?A15:A13, gA14=sA2?A16:A14, gA15=sA2?A17:A15,
        gA16=sA2?A18:A16, gA17=sA2?A19:A17, gA18=sA2?A20:A18, gA19=sA2?A21:A19,
        gA20=sA2?A22:A20, gA21=sA2?A23:A21, gA22=sA2?A24:A22, gA23=sA2?A25:A23,
        gA24=sA2?A26:A24, gA25=sA2?A27:A25, gA26=sA2?A28:A26, gA27=sA2?A29:A27,
        gA28=sA2?A30:A28, gA29=sA2?A31:A29, gA30=sA2?A32:A30, gA31=sA2?A33:A31;
      const float
        gB0 =sB2?F3 :F1,  gB1 =sB2?F4 :F2,  gB2 =sB2?F5 :F3,  gB3 =sB2?F6 :F4,
        gB4 =sB2?F7 :F5,  gB5 =sB2?F8 :F6,  gB6 =sB2?F9 :F7,  gB7 =sB2?F10:F8,
        gB8 =sB2?F11:F9,  gB9 =sB2?F12:F10, gB10=sB2?F13:F11, gB11=sB2?F14:F12,
        gB12=sB2?F15:F13, gB13=sB2?F16:F14, gB14=sB2?F17:F15, gB15=sB2?F18:F16,
        gB16=sB2?F19:F17, gB17=sB2?F20:F18, gB18=sB2?F21:F19, gB19=sB2?F22:F20,
        gB20=sB2?F23:F21, gB21=sB2?F24:F22, gB22=sB2?F25:F23, gB23=sB2?F26:F24,
        gB24=sB2?F27:F25, gB25=sB2?F28:F26, gB26=sB2?F29:F27, gB27=sB2?F30:F28,
        gB28=sB2?F31:F29, gB29=sB2?F32:F30, gB30=sB2?F33:F31, gB31=sB2?F34:F32;

      // publish pointers: row-B boundary values; b32, 8B lane stride (2-way)
      float* pE = &edgeE[w][128 + cA0 - 1];
      float* pD = &edgeD[w][128 + cA0 - 1];

#define STEP(kk, NEv, NDv, GA, GB)                                            \
      {                                                                       \
        const float eA0v = eSelfA, dA0v = dSelfA;                             \
        const float eB0v = eSelfB, dB0v = dSelfB;                             \
        const int cA = cA0 + (kk);                                            \
        const float ddLA = (GA) * NL2E;                                       \
        const float ddLAm = ((unsigned)cA < 512u) ? ddLA : -1e30f;            \
        const float ddLB = (GB) * NL2E;                                       \
        const float ddLBm = ((unsigned)(cA - 1) < 512u) ? ddLB : -1e30f;      \
        const float sEA = lane_shr1_or((NEv), eB0v);                          \
        const float sDA = lane_shr1_or((NDv), dB0v);                          \
        const float sumA = ((eN2A + eA0v) + EPS) + sEA;                       \
        const float invA = __builtin_amdgcn_rcpf(sumA);                       \
        const float numA = fmaf(eN2A, dN2A, fmaf(sEA, sDA, eA0v * dA0v));     \
        const float rrA = fmaf(invA, numA, ddLAm);                            \
        const float newEA = __builtin_amdgcn_exp2f(rrA);                      \
        const float sumB = ((eA1 + eB0v) + EPS) + eA0v;                       \
        const float invB = __builtin_amdgcn_rcpf(sumB);                       \
        const float numB = fmaf(eA1, dA1, fmaf(eA0v, dA0v, eB0v * dB0v));     \
        const float rrB = fmaf(invB, numB, ddLBm);                            \
        const float newEB = __builtin_amdgcn_exp2f(rrB);                      \
        if (d0 + (kk) == NM && t == 255) {                                    \
          out[b] = rrB * NLN2;                                                \
          out[BATCH + b] = sgA + invB * (eA1 * sg0 + eA0v * sg1 + eB0v * sg2);\
        }                                                                     \
        eN2A = sEA; dN2A = sDA;                                               \
        eA1 = eA0v; dA1 = dA0v;                                               \
        eSelfA = newEA; dSelfA = ddLA;                                        \
        eSelfB = newEB; dSelfB = ddLB;                                        \
        pE[kk] = newEB;                                                       \
        pD[kk] = ddLB;                                                        \
      }

      STEP(0,  nE0.x, nD0.x, gA0,  gB0)
      STEP(1,  nE0.y, nD0.y, gA1,  gB1)
      STEP(2,  nE0.z, nD0.z, gA2,  gB2)
      STEP(3,  nE0.w, nD0.w, gA3,  gB3)
      STEP(4,  nE1.x, nD1.x, gA4,  gB4)
      STEP(5,  nE1.y, nD1.y, gA5,  gB5)
      STEP(6,  nE1.z, nD1.z, gA6,  gB6)
      STEP(7,  nE1.w, nD1.w, gA7,  gB7)
      STEP(8,  nE2.x, nD2.x, gA8,  gB8)
      STEP(9,  nE2.y, nD2.y, gA9,  gB9)
      STEP(10, nE2.z, nD2.z, gA10, gB10)
      STEP(11, nE2.w, nD2.w, gA11, gB11)
      STEP(12, nE3.x, nD3.x, gA12, gB12)
      STEP(13, nE3.y, nD3.y, gA13, gB13)
      STEP(14, nE3.z, nD3.z, gA14, gB14)
      STEP(15, nE3.w, nD3.w, gA15, gB15)
      STEP(16, nE4.x, nD4.x, gA16, gB16)
      STEP(17, nE4.y, nD4.y, gA17, gB17)
      STEP(18, nE4.z, nD4.z, gA18, gB18)
      STEP(19, nE4.w, nD4.w, gA19, gB19)
      STEP(20, nE5.x, nD5.x, gA20, gB20)
      STEP(21, nE5.y, nD5.y, gA21, gB21)
      STEP(22, nE5.z, nD5.z, gA22, gB22)
      STEP(23, nE5.w, nD5.w, gA23, gB23)
      STEP(24, nE6.x, nD6.x, gA24, gB24)
      STEP(25, nE6.y, nD6.y, gA25, gB25)
      STEP(26, nE6.z, nD6.z, gA26, gB26)
      STEP(27, nE6.w, nD6.w, gA27, gB27)
      STEP(28, nE7.x, nD7.x, gA28, gB28)
      STEP(29, nE7.y, nD7.y, gA29, gB29)
      STEP(30, nE7.z, nD7.z, gA30, gB30)
      STEP(31, nE7.w, nD7.w, gA31, gB31)
#undef STEP
    }

    // rotate in the prefetched windows (waitcnt lands here, far from issue)
    if (dopre) {
      u0 = pu0; u1 = pu1; u2 = pu2; u3 = pu3; u4 = pu4;
      u5 = pu5; u6 = pu6; u7 = pu7; u8 = pu8;
      v0 = pv0; v1 = pv1; v2 = pv2; v3 = pv3; v4 = pv4;
      v5 = pv5; v6 = pv6; v7 = pv7; v8 = pv8;
    }
    __syncthreads();
  }
}

extern "C" void kernel_launch(void* const* d_in, const int* in_sizes, int n_in,
                              void* d_out, int out_size, void* d_ws, size_t ws_size,
                              hipStream_t stream) {
  const float* D   = (const float*)d_in[0];
  const float* Sig = (const float*)d_in[1];
  float* out = (float*)d_out;
  softdtw_fwd<<<dim3(BATCH), dim3(256), 0, stream>>>(D, Sig, out);
}